// Round 4
// baseline (431157.471 us; speedup 1.0000x reference)
//
#include <hip/hip_runtime.h>
#include <math.h>

#define SEQ   8192
#define NIN   256
#define H     2048
#define NBLK  256
#define NTHR  256

// Record: 128 B = 16 doubles. h[8] at doubles 0..7, tag (unsigned) at byte 64.
#define REC_DW 16

__device__ __forceinline__ double* rec_h(double* base, int slot, int j) {
    return base + (size_t)(slot * NBLK + j) * REC_DW;
}
__device__ __forceinline__ unsigned* rec_tag(double* base, int slot, int j) {
    return (unsigned*)(base + (size_t)(slot * NBLK + j) * REC_DW + 8);
}

// ws layout: 2 slots x 256 records x 128 B = 64 KB.
__global__ void lstm_init(const float* __restrict__ h0, double* __restrict__ ws)
{
    int j = threadIdx.x;            // 256 threads, 1 block
    double* h = rec_h(ws, 0, j);
    #pragma unroll
    for (int r = 0; r < 8; ++r) h[r] = (double)h0[8 * j + r];
    *rec_tag(ws, 0, j) = 0u;        // h0 published with tag 0
    *rec_tag(ws, 1, j) = 0u;        // slot-1 tags: never match t>=1 until written
}

// Persistent LSTM, fp64 recurrence, fp32 weights register-resident.
// Block b owns h-indices [8b, 8b+8). Wave wv computes gate wv (i,f,g,o):
// rows R = wv*H + 8b + r. Lane ln holds w_hh[R][32*ln..32*ln+32) in VGPRs.
// Sync: tag-embedded all-to-all records (no contended counter).
__global__ void __launch_bounds__(NTHR, 1)
lstm_persistent_f64(const float* __restrict__ x,
                    const float* __restrict__ c0,
                    const float* __restrict__ w_ih,
                    const float* __restrict__ w_hh,
                    const float* __restrict__ b_ih,
                    const float* __restrict__ b_hh,
                    const float* __restrict__ w_lin,
                    const float* __restrict__ b_lin,
                    float* __restrict__ out,
                    double* __restrict__ ws)
{
    const int b   = blockIdx.x;
    const int tid = threadIdx.x;
    const int wv  = tid >> 6;
    const int ln  = tid & 63;

    // padded h in LDS: +2 doubles per 32 → lane stride 272 B (2-way bank = free)
    __shared__ double h_lds[H + (H / 32) * 2];
    __shared__ double gsum[4][8];
    __shared__ double bias[4][8];
    __shared__ double act[4][8];
    __shared__ double c_sh[8];
    __shared__ double hnew[8];
    __shared__ double red0[4], red1[4];

    // ---- prologue ----
    if (tid < 32) {
        int g = tid >> 3, r = tid & 7;
        int R = g * H + b * 8 + r;
        bias[g][r] = (double)b_ih[R] + (double)b_hh[R];
    }
    if (tid < 8) c_sh[tid] = (double)c0[b * 8 + tid];

    // ---- weights into registers (fp32, once) ----
    float wreg[8][32];
    float wih[8][4];
    #pragma unroll
    for (int r = 0; r < 8; ++r) {
        const int R = wv * H + b * 8 + r;
        const float4* wp = (const float4*)(w_hh + (size_t)R * H + ln * 32);
        #pragma unroll
        for (int q = 0; q < 8; ++q) ((float4*)wreg[r])[q] = wp[q];
        *(float4*)wih[r] = *(const float4*)(w_ih + (size_t)R * NIN + ln * 4);
    }
    __syncthreads();

    float4 xr = *(const float4*)(x + ln * 4);   // x(0) slice
    float4 xn = xr;

    // ---- 8192-step recurrence ----
    for (int t = 0; t < SEQ; ++t) {
        const int slot = t & 1;

        // phase A: thread j waits for record j of this step, deposits to LDS
        {
            unsigned* tg = rec_tag(ws, slot, tid);
            while (__hip_atomic_load(tg, __ATOMIC_ACQUIRE,
                                     __HIP_MEMORY_SCOPE_AGENT) != (unsigned)t) {}
            const double* hr = rec_h(ws, slot, tid);
            const int pj = 8 * tid + (tid >> 2) * 2;   // padded base of logical 8*tid
            #pragma unroll
            for (int r = 0; r < 8; ++r) h_lds[pj + r] = hr[r];
        }
        __syncthreads();

        // prefetch next x slice (latency hides under FMA work / next poll)
        if (t + 1 < SEQ)
            xn = *(const float4*)(x + (size_t)(t + 1) * NIN + ln * 4);

        // phase B: matvec — lane's 32-double chunk from padded LDS
        double hreg[32];
        {
            const double* hp = &h_lds[34 * ln];
            #pragma unroll
            for (int q = 0; q < 32; ++q) hreg[q] = hp[q];
        }
        const double xd0 = xr.x, xd1 = xr.y, xd2 = xr.z, xd3 = xr.w;

        double acc[8];
        #pragma unroll
        for (int r = 0; r < 8; ++r) {
            double a = (double)wih[r][0] * xd0 + (double)wih[r][1] * xd1
                     + (double)wih[r][2] * xd2 + (double)wih[r][3] * xd3;
            #pragma unroll
            for (int q = 0; q < 32; ++q)
                a = fma((double)wreg[r][q], hreg[q], a);
            acc[r] = a;
        }

        #pragma unroll
        for (int off = 32; off >= 1; off >>= 1) {
            #pragma unroll
            for (int r = 0; r < 8; ++r)
                acc[r] += __shfl_xor(acc[r], off, 64);
        }

        if (ln == 0) {
            #pragma unroll
            for (int r = 0; r < 8; ++r) gsum[wv][r] = acc[r];
        }
        __syncthreads();

        if (tid < 32) {
            const int g = tid >> 3, j = tid & 7;
            double v = gsum[g][j] + bias[g][j];
            act[g][j] = (g == 2) ? tanh(v) : 1.0 / (1.0 + exp(-v));
        }
        __syncthreads();

        if (tid < 8) {
            const int j = tid;
            double c = act[1][j] * c_sh[j] + act[0][j] * act[2][j];
            c_sh[j] = c;
            hnew[j] = act[3][j] * tanh(c);
        }
        __syncthreads();

        // phase D: publish this block's 8 new h values with tag t+1
        if (tid == 0) {
            double* dst = rec_h(ws, 1 - slot, b);
            #pragma unroll
            for (int r = 0; r < 8; ++r) dst[r] = hnew[r];
            __threadfence();   // agent-scope release of the data stores
            __hip_atomic_store(rec_tag(ws, 1 - slot, b), (unsigned)(t + 1),
                               __ATOMIC_RELEASE, __HIP_MEMORY_SCOPE_AGENT);
        }
        xr = xn;
    }

    // ---- final gather: h(SEQ) lives in slot[SEQ&1 == 0] with tag SEQ ----
    {
        unsigned* tg = rec_tag(ws, SEQ & 1, tid);
        while (__hip_atomic_load(tg, __ATOMIC_ACQUIRE,
                                 __HIP_MEMORY_SCOPE_AGENT) != (unsigned)SEQ) {}
        const double* hr = rec_h(ws, SEQ & 1, tid);
        const int pj = 8 * tid + (tid >> 2) * 2;
        #pragma unroll
        for (int r = 0; r < 8; ++r) h_lds[pj + r] = hr[r];
    }
    __syncthreads();

    // ---- epilogue: block 0 computes the 2 logits ----
    if (b == 0) {
        double a0 = 0., a1 = 0.;
        #pragma unroll
        for (int k = 0; k < 8; ++k) {
            int j = tid + k * NTHR;
            double hv = h_lds[j + (j >> 5) * 2];
            a0 = fma((double)w_lin[j],     hv, a0);
            a1 = fma((double)w_lin[H + j], hv, a1);
        }
        #pragma unroll
        for (int off = 32; off >= 1; off >>= 1) {
            a0 += __shfl_xor(a0, off, 64);
            a1 += __shfl_xor(a1, off, 64);
        }
        if (ln == 0) { red0[wv] = a0; red1[wv] = a1; }
        __syncthreads();
        if (tid == 0) {
            out[0] = (float)(red0[0] + red0[1] + red0[2] + red0[3] + (double)b_lin[0]);
            out[1] = (float)(red1[0] + red1[1] + red1[2] + red1[3] + (double)b_lin[1]);
        }
    }
}

extern "C" void kernel_launch(void* const* d_in, const int* in_sizes, int n_in,
                              void* d_out, int out_size, void* d_ws, size_t ws_size,
                              hipStream_t stream) {
    const float* x     = (const float*)d_in[0];
    const float* h0    = (const float*)d_in[1];
    const float* c0    = (const float*)d_in[2];
    const float* w_ih  = (const float*)d_in[3];
    const float* w_hh  = (const float*)d_in[4];
    const float* b_ih  = (const float*)d_in[5];
    const float* b_hh  = (const float*)d_in[6];
    const float* w_lin = (const float*)d_in[7];
    const float* b_lin = (const float*)d_in[8];
    float*  out = (float*)d_out;
    double* ws  = (double*)d_ws;

    lstm_init<<<1, NTHR, 0, stream>>>(h0, ws);
    lstm_persistent_f64<<<NBLK, NTHR, 0, stream>>>(
        x, c0, w_ih, w_hh, b_ih, b_hh, w_lin, b_lin, out, ws);
}

// Round 5
// 176525.769 us; speedup vs baseline: 2.4425x; 2.4425x over previous
//
#include <hip/hip_runtime.h>
#include <math.h>

#define SEQ   8192
#define NIN   256
#define H     2048
#define NBLK  256
#define NTHR  256

typedef unsigned long long u64;

// ---- ws layout (bytes from d_ws) ----
// 0     : float hA[2][H]          (16 KB) fp32 h transport, ping-pong
// 16384 : unsigned tags[2][NBLK]  (2 KB)  tag[slot][b] = step count of record
__global__ void lstm_init(const float* __restrict__ h0, float* __restrict__ ws)
{
    const int j = threadIdx.x;   // one block of 256
    unsigned* tags = (unsigned*)(ws + 2 * H);
    #pragma unroll
    for (int r = 0; r < 8; ++r) ws[8 * j + r] = h0[8 * j + r];
    tags[j]        = 0u;           // slot 0 carries h_0 with tag 0
    tags[NBLK + j] = 0xFFFFFFFFu;  // slot 1 not ready
}

// Wave-0-only poll: lane ln checks packed tag pairs (2 u64 = 4 tags) until all
// 256 tags == t. RELAXED agent atomics: sc1 loads reach the coherence point
// with NO per-iteration cache-invalidate (the round-3/4 killer).
__device__ __forceinline__ void wave_poll_tags(const u64* tp, unsigned t, int ln)
{
    const u64 want = ((u64)t << 32) | (u64)t;
    for (;;) {
        u64 a = __hip_atomic_load(tp + ln,      __ATOMIC_RELAXED, __HIP_MEMORY_SCOPE_AGENT);
        u64 b = __hip_atomic_load(tp + 64 + ln, __ATOMIC_RELAXED, __HIP_MEMORY_SCOPE_AGENT);
        if (__all((a == want) && (b == want))) break;
        __builtin_amdgcn_s_sleep(2);
    }
}

// Persistent LSTM. fp32 weights register-resident, fp64 recurrence math,
// fp32 h transport. Block b owns h[8b..8b+8); wave wv computes gate wv.
// Lane ln holds w_hh[R][32ln..32ln+32) for its 8 rows. No fences in hot loop.
__global__ void __launch_bounds__(NTHR, 1)
lstm_persist(const float* __restrict__ x, const float* __restrict__ c0,
             const float* __restrict__ w_ih, const float* __restrict__ w_hh,
             const float* __restrict__ b_ih, const float* __restrict__ b_hh,
             const float* __restrict__ w_lin, const float* __restrict__ b_lin,
             float* __restrict__ out, float* __restrict__ ws)
{
    const int b = blockIdx.x, tid = threadIdx.x;
    const int wv = tid >> 6, ln = tid & 63;
    float*     hA    = ws;
    unsigned*  tags  = (unsigned*)(ws + 2 * H);
    const u64* tagsU = (const u64*)tags;

    __shared__ float  h_lds[H + H / 32];   // stride-33 padding: 2-way bank = free
    __shared__ double gsum[4][8];
    __shared__ double bias_s[4][8];
    __shared__ double red0[4], red1[4];

    if (tid < 32) {
        int g = tid >> 3, r = tid & 7;
        int R = g * H + b * 8 + r;
        bias_s[g][r] = (double)b_ih[R] + (double)b_hh[R];
    }
    // cell state lives in wave-0 registers (lane j<8 owns c[8b+j])
    double c_reg = (wv == 0 && ln < 8) ? (double)c0[b * 8 + ln] : 0.0;

    float wreg[8][32];
    float wih[8][4];
    #pragma unroll
    for (int r = 0; r < 8; ++r) {
        const int R = wv * H + b * 8 + r;
        const float4* wp = (const float4*)(w_hh + (size_t)R * H + ln * 32);
        #pragma unroll
        for (int q = 0; q < 8; ++q) ((float4*)wreg[r])[q] = wp[q];
        *(float4*)wih[r] = *(const float4*)(w_ih + (size_t)R * NIN + ln * 4);
    }
    __syncthreads();

    float4 xr = *(const float4*)(x + ln * 4);
    float4 xn = xr;

    for (int t = 0; t < SEQ; ++t) {
        const int slot = t & 1;

        if (wv == 0) wave_poll_tags(tagsU + slot * (NBLK / 2), (unsigned)t, ln);
        __syncthreads();   // #1: all 256 records of step t are at coherence point

        // fetch h: thread tid owns floats [8*tid, 8*tid+8) -> padded LDS
        {
            const u64* hp = (const u64*)(hA + slot * H) + tid * 4;
            const int base = 8 * tid + (tid >> 2);
            #pragma unroll
            for (int q = 0; q < 4; ++q) {
                u64 v = __hip_atomic_load(hp + q, __ATOMIC_RELAXED, __HIP_MEMORY_SCOPE_AGENT);
                union { u64 u; float2 f; } cv; cv.u = v;
                h_lds[base + 2 * q]     = cv.f.x;
                h_lds[base + 2 * q + 1] = cv.f.y;
            }
        }
        __syncthreads();   // #2

        if (t + 1 < SEQ) xn = *(const float4*)(x + (size_t)(t + 1) * NIN + ln * 4);

        // matvec: fp32 w x fp32 h, fp64 accumulate
        float hbuf[32];
        {
            const float* hp = &h_lds[33 * ln];
            #pragma unroll
            for (int q = 0; q < 32; ++q) hbuf[q] = hp[q];
        }
        double acc[8];
        #pragma unroll
        for (int r = 0; r < 8; ++r)
            acc[r] = (double)wih[r][0] * (double)xr.x + (double)wih[r][1] * (double)xr.y
                   + (double)wih[r][2] * (double)xr.z + (double)wih[r][3] * (double)xr.w;
        #pragma unroll
        for (int q = 0; q < 32; ++q) {
            const double hq = (double)hbuf[q];
            #pragma unroll
            for (int r = 0; r < 8; ++r)
                acc[r] = fma((double)wreg[r][q], hq, acc[r]);
        }
        #pragma unroll
        for (int off = 32; off >= 1; off >>= 1) {
            #pragma unroll
            for (int r = 0; r < 8; ++r) acc[r] += __shfl_xor(acc[r], off, 64);
        }
        if (ln == 0) {
            #pragma unroll
            for (int r = 0; r < 8; ++r) gsum[wv][r] = acc[r];
        }
        __syncthreads();   // #3

        // wave 0: activations (lanes 0-31, one each), update, publish
        if (wv == 0) {
            double actv = 0.0;
            if (ln < 32) {
                const int g = ln >> 3, j = ln & 7;
                double v = gsum[g][j] + bias_s[g][j];
                actv = (g == 2) ? tanh(v) : 1.0 / (1.0 + exp(-v));
            }
            const int j = ln & 7;
            double ai = __shfl(actv, j,      64);
            double af = __shfl(actv, j + 8,  64);
            double ag = __shfl(actv, j + 16, 64);
            double ao = __shfl(actv, j + 24, 64);
            if (ln < 8) {
                double c = af * c_reg + ai * ag;
                c_reg = c;
                float hnew = (float)(ao * tanh(c));
                unsigned* dst = (unsigned*)(hA + (1 - slot) * H) + 8 * b + ln;
                __hip_atomic_store(dst, __builtin_bit_cast(unsigned, hnew),
                                   __ATOMIC_RELAXED, __HIP_MEMORY_SCOPE_AGENT);
            }
            // order data stores before tag store (atomic->atomic: waitcnt suffices)
            asm volatile("s_waitcnt vmcnt(0)" ::: "memory");
            if (ln == 0)
                __hip_atomic_store(&tags[(1 - slot) * NBLK + b], (unsigned)(t + 1),
                                   __ATOMIC_RELAXED, __HIP_MEMORY_SCOPE_AGENT);
        }
        xr = xn;
    }

    // ---- epilogue: block 0 computes logits from h(SEQ) (slot 0, tag SEQ) ----
    if (b == 0) {
        if (wv == 0) wave_poll_tags(tagsU, (unsigned)SEQ, ln);
        __syncthreads();
        double a0 = 0., a1 = 0.;
        {
            const u64* hp = (const u64*)hA + tid * 4;
            #pragma unroll
            for (int q = 0; q < 4; ++q) {
                u64 v = __hip_atomic_load(hp + q, __ATOMIC_RELAXED, __HIP_MEMORY_SCOPE_AGENT);
                union { u64 u; float2 f; } cv; cv.u = v;
                const int k = 8 * tid + 2 * q;
                a0 = fma((double)w_lin[k],         (double)cv.f.x, a0);
                a0 = fma((double)w_lin[k + 1],     (double)cv.f.y, a0);
                a1 = fma((double)w_lin[H + k],     (double)cv.f.x, a1);
                a1 = fma((double)w_lin[H + k + 1], (double)cv.f.y, a1);
            }
        }
        #pragma unroll
        for (int off = 32; off >= 1; off >>= 1) {
            a0 += __shfl_xor(a0, off, 64);
            a1 += __shfl_xor(a1, off, 64);
        }
        if (ln == 0) { red0[wv] = a0; red1[wv] = a1; }
        __syncthreads();
        if (tid == 0) {
            out[0] = (float)(red0[0] + red0[1] + red0[2] + red0[3] + (double)b_lin[0]);
            out[1] = (float)(red1[0] + red1[1] + red1[2] + red1[3] + (double)b_lin[1]);
        }
    }
}

extern "C" void kernel_launch(void* const* d_in, const int* in_sizes, int n_in,
                              void* d_out, int out_size, void* d_ws, size_t ws_size,
                              hipStream_t stream) {
    const float* x     = (const float*)d_in[0];
    const float* h0    = (const float*)d_in[1];
    const float* c0    = (const float*)d_in[2];
    const float* w_ih  = (const float*)d_in[3];
    const float* w_hh  = (const float*)d_in[4];
    const float* b_ih  = (const float*)d_in[5];
    const float* b_hh  = (const float*)d_in[6];
    const float* w_lin = (const float*)d_in[7];
    const float* b_lin = (const float*)d_in[8];
    float* out = (float*)d_out;
    float* ws  = (float*)d_ws;

    lstm_init<<<1, NTHR, 0, stream>>>(h0, ws);
    lstm_persist<<<NBLK, NTHR, 0, stream>>>(
        x, c0, w_ih, w_hh, b_ih, b_hh, w_lin, b_lin, out, ws);
}